// Round 8
// baseline (165.000 us; speedup 1.0000x reference)
//
#include <hip/hip_runtime.h>
#include <hip/hip_bf16.h>
#include <cstddef>
#include <cstdint>

typedef float v4f __attribute__((ext_vector_type(4)));
typedef short v8s __attribute__((ext_vector_type(8)));
typedef _Float16 v8h __attribute__((ext_vector_type(8)));

__device__ __forceinline__ uint32_t fbits(float x){ uint32_t u; __builtin_memcpy(&u,&x,4); return u; }
__device__ __forceinline__ float ffrom(uint32_t u){ float f; __builtin_memcpy(&f,&u,4); return f; }
// round-half-up bf16
__device__ __forceinline__ short bf_rh(float x){ return (short)((fbits(x)+0x8000u)>>16); }
__device__ __forceinline__ uint32_t pack_bf_rh(float a, float b){
    uint32_t ua = fbits(a)+0x8000u, ub = fbits(b)+0x8000u;
#if __has_builtin(__builtin_amdgcn_perm)
    return __builtin_amdgcn_perm(ub, ua, 0x07060302u);
#else
    return (ua>>16) | (ub & 0xFFFF0000u);
#endif
}
// fp16 (RNE) stored in a short
__device__ __forceinline__ short f2h(float x){ _Float16 h = (_Float16)x; short s; __builtin_memcpy(&s,&h,2); return s; }
#if __has_builtin(__builtin_amdgcn_exp2f)
#define EXP2(x) __builtin_amdgcn_exp2f(x)
#else
#define EXP2(x) exp2f(x)
#endif

__device__ __forceinline__ void gld16(const void* g, void* l) {
    __builtin_amdgcn_global_load_lds(
        (const __attribute__((address_space(1))) unsigned int*)g,
        (__attribute__((address_space(3))) unsigned int*)l, 16, 0, 0);
}
#define MFMA(a,b,c)  __builtin_amdgcn_mfma_f32_16x16x32_bf16((a),(b),(c),0,0,0)
#define MFMAH(a,b,c) __builtin_amdgcn_mfma_f32_16x16x32_f16((a),(b),(c),0,0,0)

#define LOG2E 1.4426950408889634f

// ---------------------------------------------------------------------------
// CPB MLP, single launch, no atomics: 63 blocks x 63 rows; 4 threads per row
// split the 512 hidden dim, shuffle-reduce partials.
// ---------------------------------------------------------------------------
__global__ __launch_bounds__(256)
void cpb_kernel(const float* __restrict__ rct,
                const float* __restrict__ fc1w, const float* __restrict__ fc1b,
                const float* __restrict__ fc2w, const float* __restrict__ fc2b,
                float* __restrict__ table)
{
    __shared__ float s1[1024];
    __shared__ float sb[512];
    __shared__ float s2[4096];
    int tid = threadIdx.x;
    for (int i = tid; i < 1024; i += 256) s1[i] = fc1w[i];
    for (int i = tid; i < 512;  i += 256) sb[i] = fc1b[i];
    for (int i = tid; i < 4096; i += 256) s2[i] = fc2w[i];
    __syncthreads();
    int rl = tid >> 2, jp = tid & 3;
    bool ok = rl < 63;
    int r = blockIdx.x * 63 + rl;
    float c0 = ok ? rct[2*r]   : 0.f;
    float c1 = ok ? rct[2*r+1] : 0.f;
    float a[8] = {0,0,0,0,0,0,0,0};
    int j0 = jp * 128;
    #pragma unroll 4
    for (int j = j0; j < j0 + 128; ++j) {
        float hv = fmaxf(c0*s1[2*j] + c1*s1[2*j+1] + sb[j], 0.0f);
        #pragma unroll
        for (int hh = 0; hh < 8; ++hh) a[hh] += hv * s2[hh*512 + j];
    }
    #pragma unroll
    for (int hh = 0; hh < 8; ++hh) {
        a[hh] += __shfl_xor(a[hh], 1);
        a[hh] += __shfl_xor(a[hh], 2);
    }
    if (ok && jp == 0) {
        #pragma unroll
        for (int hh = 0; hh < 8; ++hh) table[hh*3969 + r] = a[hh] + fc2b[hh];
    }
}

// ---------------------------------------------------------------------------
// Materialize relative-position bias as bf16, scaled by log2(e), in MFMA
// C-fragment order matching the permuted K staging (key kt*64 + 4t + g).
// Layout: [h][q16(64)][kt(16)][g(4)][lane(64)][4 shorts] = 16 MB.
// ---------------------------------------------------------------------------
__global__ __launch_bounds__(256)
void bias_mat(const float* __restrict__ tblf, const int* __restrict__ rpi,
              short* __restrict__ biasM)
{
    __shared__ float tb[3969];
    int h   = blockIdx.x >> 6;
    int q16 = blockIdx.x & 63;
    int tid = threadIdx.x;
    int w = tid >> 6, lane = tid & 63, t = lane & 15, quad = lane >> 4;
    for (int i = tid; i < 3969; i += 256) tb[i] = tblf[h*3969 + i] * LOG2E;
    __syncthreads();
    int row0 = q16*16 + quad*4;
    #pragma unroll 1
    for (int kk = 0; kk < 4; ++kk) {
        int kt = w*4 + kk;
        #pragma unroll
        for (int g = 0; g < 4; ++g) {
            float o[4];
            #pragma unroll
            for (int r = 0; r < 4; ++r)
                o[r] = tb[rpi[(size_t)(row0 + r)*1024 + kt*64 + 4*t + g]];
            uint2 pk;
            pk.x = pack_bf_rh(o[0], o[1]);
            pk.y = pack_bf_rh(o[2], o[3]);
            size_t base = ((((size_t)(h*64 + q16)*16 + kt)*4 + g)*64 + lane)*4;
            *(uint2*)(biasM + base) = pk;
        }
    }
}

// ---------------------------------------------------------------------------
// fp32 -> fp16, 16B-chunk-swizzled: chunk c of row m stored at chunk
// (c ^ (m&7)) within its 64-elem K-tile. Inner dim K=256.
// ---------------------------------------------------------------------------
__global__ __launch_bounds__(256)
void split_kernel(const float* __restrict__ x,  short* __restrict__ xh,
                  const float* __restrict__ wq, short* __restrict__ wqh,
                  const float* __restrict__ wp, short* __restrict__ wph)
{
    int bid = blockIdx.x;
    const float* src; short* dh; int base8;
    if (bid < 1024)      { src = x;  dh = xh;  base8 = bid * 256; }
    else if (bid < 1120) { src = wq; dh = wqh; base8 = (bid-1024) * 256; }
    else                 { src = wp; dh = wph; base8 = (bid-1120) * 256; }
    int e0 = (base8 + (int)threadIdx.x) * 8;
    int m  = e0 >> 8;
    int k  = e0 & 255;
    int kt = k >> 6, c = (k >> 3) & 7;
    float4 f0 = *(const float4*)(src + e0);
    float4 f1 = *(const float4*)(src + e0 + 4);
    float v[8] = {f0.x,f0.y,f0.z,f0.w,f1.x,f1.y,f1.z,f1.w};
    v8s hi;
    #pragma unroll
    for (int j = 0; j < 8; ++j) hi[j] = f2h(v[j]);
    int dst = m*256 + kt*64 + ((c ^ (m & 7)) << 3);
    *(v8s*)&dh[dst] = hi;
}

// ---------------------------------------------------------------------------
// fp16 1-pass MFMA GEMM: C = A(MxK=256) * W(NxK=256)^T + bias.
// TM=128, TN=64, BK=64, 256 threads = 4 waves (2x2 wave grid).
// MODE 0: plain fp32 C [M][N] (proj).
// MODE 1 (qkv): q: l2norm + qe + softplus(temp)*10, fp16 plain layout;
//   k: l2norm, fp16 KEY-PERMUTED within 64-tiles + chunk-swizzled;
//   v: bf16 transposed to vt[bh][32][1024] (chunk-swizzled) via LDS.
// ---------------------------------------------------------------------------
template<int MODE>
__global__ __launch_bounds__(256)
void gemm_mfma(const short* __restrict__ Ah_g, const short* __restrict__ Wh_g,
               const float* __restrict__ bias, float* __restrict__ C,
               short* __restrict__ qh, short* __restrict__ kh,
               short* __restrict__ vt,
               const float* __restrict__ qe, const float* __restrict__ temp,
               int N)
{
    __shared__ __align__(16) char smem[24576];
    short* Ah = (short*)smem;          // [128][64] fp16
    short* Wh = Ah + 128*64;           // [64][64]  fp16

    int tid  = threadIdx.x;
    int w    = tid >> 6;
    int lane = tid & 63;
    int t    = lane & 15;
    int quad = lane >> 4;
    int m0 = blockIdx.y * 128, n0 = blockIdx.x * 64;
    int Mw = (w >> 1) * 64, Nw = (w & 1) * 32;

    v4f acc[4][2];
    #pragma unroll
    for (int mt = 0; mt < 4; ++mt)
        #pragma unroll
        for (int nt = 0; nt < 2; ++nt) acc[mt][nt] = (v4f){0,0,0,0};

    int lr8 = lane >> 3, lc8 = lane & 7;
    #pragma unroll 1
    for (int kt = 0; kt < 4; ++kt) {
        __syncthreads();
        #pragma unroll
        for (int i = 0; i < 4; ++i) {
            size_t grow = (size_t)(m0 + w*32 + i*8 + lr8) * 256 + kt*64 + lc8*8;
            gld16(Ah_g + grow, Ah + (w*32 + i*8) * 64);
        }
        #pragma unroll
        for (int i = 0; i < 2; ++i) {
            size_t grow = (size_t)(n0 + w*16 + i*8 + lr8) * 256 + kt*64 + lc8*8;
            gld16(Wh_g + grow, Wh + (w*16 + i*8) * 64);
        }
        __syncthreads();
        #pragma unroll
        for (int kk = 0; kk < 2; ++kk) {
            int cp = ((kk*4 + quad) ^ (t & 7)) << 3;
            v8h bh8[2];
            #pragma unroll
            for (int nt = 0; nt < 2; ++nt)
                bh8[nt] = *(const v8h*)&Wh[(Nw + nt*16 + t)*64 + cp];
            #pragma unroll
            for (int mt = 0; mt < 4; ++mt) {
                v8h ah = *(const v8h*)&Ah[(Mw + mt*16 + t)*64 + cp];
                #pragma unroll
                for (int nt = 0; nt < 2; ++nt)
                    acc[mt][nt] = MFMAH(ah, bh8[nt], acc[mt][nt]);
            }
        }
    }

    // bias
    #pragma unroll
    for (int nt = 0; nt < 2; ++nt) {
        float bv = bias[n0 + Nw + nt*16 + t];
        #pragma unroll
        for (int mt = 0; mt < 4; ++mt)
            #pragma unroll
            for (int r = 0; r < 4; ++r) acc[mt][nt][r] += bv;
    }

    if (MODE == 0) {
        #pragma unroll
        for (int mt = 0; mt < 4; ++mt)
            #pragma unroll
            for (int r = 0; r < 4; ++r) {
                int m = m0 + Mw + mt*16 + quad*4 + r;
                #pragma unroll
                for (int nt = 0; nt < 2; ++nt)
                    C[(size_t)m * N + n0 + Nw + nt*16 + t] = acc[mt][nt][r];
            }
    } else {
        int which = n0 >> 8;
        if (which < 2) {
            int head = ((n0 + Nw) >> 5) & 7;
            float scale = 0.f;
            if (which == 0)
                scale = log1pf(__expf(temp[head])) * 10.0f;  // softplus*ln(1024)*log2e
            #pragma unroll
            for (int mt = 0; mt < 4; ++mt)
                #pragma unroll
                for (int r = 0; r < 4; ++r) {
                    float a0 = acc[mt][0][r], a1 = acc[mt][1][r];
                    float s = a0*a0 + a1*a1;
                    s += __shfl_xor(s, 1); s += __shfl_xor(s, 2);
                    s += __shfl_xor(s, 4); s += __shfl_xor(s, 8);
                    float inv = 1.0f / fmaxf(sqrtf(s), 1e-12f);
                    int m = m0 + Mw + mt*16 + quad*4 + r;
                    int b = m >> 10, nrow = m & 1023;
                    if (which == 0) {
                        size_t rowoff = (((size_t)b*8 + head)*1024 + nrow) * 32;
                        #pragma unroll
                        for (int nt = 0; nt < 2; ++nt) {
                            int d = nt*16 + t;
                            float val = (acc[mt][nt][r] * inv + qe[head*32 + d]) * scale;
                            qh[rowoff + d] = f2h(val);
                        }
                    } else {
                        int kk = nrow & 63;
                        int p  = (kk & 3)*16 + (kk >> 2);
                        int prow = (nrow & ~63) | p;
                        int swk = (kk >> 3) & 3;
                        size_t rowoff = (((size_t)b*8 + head)*1024 + prow) * 32;
                        #pragma unroll
                        for (int nt = 0; nt < 2; ++nt) {
                            int d = nt*16 + t;
                            int dpos = (((d >> 3) ^ swk) << 3) | (d & 7);
                            kh[rowoff + dpos] = f2h(acc[mt][nt][r] * inv);
                        }
                    }
                }
        } else {
            // v: transpose via LDS, write vt[bh][dim][key] bf16, tile-swizzled
            __syncthreads();
            short* VT = (short*)smem;        // [64][136]
            #pragma unroll
            for (int mt = 0; mt < 4; ++mt)
                #pragma unroll
                for (int nt = 0; nt < 2; ++nt) {
                    int cl = Nw + nt*16 + t;
                    #pragma unroll
                    for (int r = 0; r < 4; ++r) {
                        int rl = Mw + mt*16 + quad*4 + r;
                        VT[cl*136 + rl] = bf_rh(acc[mt][nt][r]);
                    }
                }
            __syncthreads();
            int b = m0 >> 10;
            int keybase = m0 & 1023;
            int headbase = ((n0 - 512) >> 5) & 7;
            int cl = tid >> 2;
            int dim = cl & 31;
            int hd  = headbase + (cl >> 5);
            size_t obase = (((size_t)b*8 + hd)*32 + dim) * 1024 + keybase;
            #pragma unroll
            for (int p = 0; p < 4; ++p) {
                int ci  = (tid & 3) * 4 + p;
                int ktl = ci >> 3, c = ci & 7;
                v8s val = *(const v8s*)&VT[cl*136 + ktl*64 + c*8];
                *(v8s*)&vt[obase + ktl*64 + ((c ^ (dim & 7)) << 3)] = val;
            }
        }
    }
}

// ---------------------------------------------------------------------------
// MFMA flash attention, exp2 domain, fp16 QK^T, bf16 PV. K/V/bias fragments
// are DIRECT global->VGPR loads (pre-permuted/pre-swizzled layouts make them
// coalesced), software-pipelined one tile ahead. LDS holds only the per-wave
// P buffer (C-layout -> A-layout transit) — NO barriers in the K-loop.
// Output: swizzled fp16 y for the 1-pass fp16 proj GEMM.
// ---------------------------------------------------------------------------
__global__ __launch_bounds__(256)
void attn_mfma(const short* __restrict__ qh, const short* __restrict__ kh,
               const short* __restrict__ vt,  const short* __restrict__ biasM,
               short* __restrict__ yh)
{
    __shared__ __align__(16) short Ps[4][16][68];   // per-wave P (bf16, cols=keys)

    int bh  = blockIdx.x >> 4;
    int qt  = blockIdx.x & 15;
    int h   = bh & 7;
    int b   = bh >> 3;
    int tid = threadIdx.x;
    int w    = tid >> 6;
    int lane = tid & 63;
    int t    = lane & 15;
    int quad = lane >> 4;

    size_t qoff = ((size_t)bh*1024 + qt*64 + w*16 + t) * 32 + quad*8;
    v8h qf = *(const v8h*)(qh + qoff);

    v4f Oacc[2] = {{0,0,0,0},{0,0,0,0}};
    float lsum[4] = {0,0,0,0};

    const short* kbase = kh + (size_t)bh*32768;
    const short* vbase = vt + (size_t)bh*32768;
    const short* bmb = biasM + ((size_t)(h*64 + qt*4 + w) * 16) * 1024 + lane*4;
    int qrow0 = qt*64 + w*16 + quad*4;
    int swzS = (quad ^ ((t >> 1) & 3)) << 3;

    // fragment offsets (same addressing the LDS staging used, minus the LDS)
    int koff[4], voff[2][2];
    #pragma unroll
    for (int g = 0; g < 4; ++g) koff[g] = (g*16 + t)*32 + swzS;
    #pragma unroll
    for (int ks = 0; ks < 2; ++ks)
        #pragma unroll
        for (int g = 0; g < 2; ++g)
            voff[ks][g] = (g*16 + t)*1024 + (((ks*4 + quad) ^ (t & 7)) << 3);

    // prefetch tile 0
    v8h Kc[4]; v8s Vc[2][2]; uint2 Bc[4];
    #pragma unroll
    for (int g = 0; g < 4; ++g) Kc[g] = *(const v8h*)(kbase + koff[g]);
    #pragma unroll
    for (int ks = 0; ks < 2; ++ks)
        #pragma unroll
        for (int g = 0; g < 2; ++g) Vc[ks][g] = *(const v8s*)(vbase + voff[ks][g]);
    #pragma unroll
    for (int g = 0; g < 4; ++g) Bc[g] = *(const uint2*)(bmb + g*256);

    #pragma unroll 2
    for (int kt = 0; kt < 16; ++kt) {
        v8h Kn[4]; v8s Vn[2][2]; uint2 Bn[4];
        if (kt < 15) {
            const short* kp = kbase + (kt+1)*2048;
            const short* vp = vbase + (kt+1)*64;
            const short* bp = bmb + (size_t)(kt+1)*1024;
            #pragma unroll
            for (int g = 0; g < 4; ++g) Kn[g] = *(const v8h*)(kp + koff[g]);
            #pragma unroll
            for (int ks = 0; ks < 2; ++ks)
                #pragma unroll
                for (int g = 0; g < 2; ++g) Vn[ks][g] = *(const v8s*)(vp + voff[ks][g]);
            #pragma unroll
            for (int g = 0; g < 4; ++g) Bn[g] = *(const uint2*)(bp + g*256);
        }

        // S = bias + Q K^T (fp16, 1 pass), exp2 domain
        v4f S[4];
        #pragma unroll
        for (int g = 0; g < 4; ++g) {
            v4f c;
            c[0] = ffrom(Bc[g].x << 16);
            c[1] = ffrom(Bc[g].x & 0xFFFF0000u);
            c[2] = ffrom(Bc[g].y << 16);
            c[3] = ffrom(Bc[g].y & 0xFFFF0000u);
            S[g] = MFMAH(qf, Kc[g], c);
        }

        // p = exp2(S); P cols are contiguous actual keys 4t+g -> packed b64
        #pragma unroll
        for (int r = 0; r < 4; ++r) {
            float p0 = EXP2(S[0][r]);
            float p1 = EXP2(S[1][r]);
            float p2 = EXP2(S[2][r]);
            float p3 = EXP2(S[3][r]);
            lsum[r] += (p0 + p1) + (p2 + p3);
            uint2 pk;
            pk.x = pack_bf_rh(p0, p1);
            pk.y = pack_bf_rh(p2, p3);
            *(uint2*)&Ps[w][quad*4 + r][t*4] = pk;
        }

        // O += P V (same-wave LDS dependency only)
        #pragma unroll
        for (int ks = 0; ks < 2; ++ks) {
            v8s pf = *(const v8s*)&Ps[w][t][ks*32 + quad*8];
            #pragma unroll
            for (int g = 0; g < 2; ++g)
                Oacc[g] = MFMA(pf, Vc[ks][g], Oacc[g]);
        }

        #pragma unroll
        for (int g = 0; g < 4; ++g) { Kc[g] = Kn[g]; Bc[g] = Bn[g]; }
        #pragma unroll
        for (int ks = 0; ks < 2; ++ks)
            #pragma unroll
            for (int g = 0; g < 2; ++g) Vc[ks][g] = Vn[ks][g];
    }

    // epilogue: reduce l, normalize, write swizzled fp16 y
    #pragma unroll
    for (int r = 0; r < 4; ++r) {
        float l = lsum[r];
        l += __shfl_xor(l, 1); l += __shfl_xor(l, 2);
        l += __shfl_xor(l, 4); l += __shfl_xor(l, 8);
        float inv = 1.0f / l;
        int qrow = qrow0 + r;
        int m = b*1024 + qrow;
        size_t mbase = (size_t)m * 256;
        int mk = m & 7;
        #pragma unroll
        for (int g = 0; g < 2; ++g) {
            float o = Oacc[g][r] * inv;
            int c = h*4 + g*2 + (t >> 3);
            int chp = ((c ^ mk) << 3) | (t & 7);
            yh[mbase + chp] = f2h(o);
        }
    }
}

// ---------------------------------------------------------------------------
extern "C" void kernel_launch(void* const* d_in, const int* in_sizes, int n_in,
                              void* d_out, int out_size, void* d_ws, size_t ws_size,
                              hipStream_t stream)
{
    const float* x     = (const float*)d_in[0];
    const int*   rpi   = (const int*)d_in[3];
    const float* rct   = (const float*)d_in[4];
    const float* qkvw  = (const float*)d_in[5];
    const float* qkvb  = (const float*)d_in[6];
    const float* qe    = (const float*)d_in[7];
    const float* temp  = (const float*)d_in[8];
    const float* projw = (const float*)d_in[9];
    const float* projb = (const float*)d_in[10];
    const float* fc1w  = (const float*)d_in[11];
    const float* fc1b  = (const float*)d_in[12];
    const float* fc2w  = (const float*)d_in[13];
    const float* fc2b  = (const float*)d_in[14];

    char* p = (char*)d_ws;
    float* tblf  = (float*)p;  p += 131072;
    short* xh    = (short*)p;  p += 4194304;   // reused as y (fp16) after attn
    short* wqh   = (short*)p;  p += 393216;
    short* wph   = (short*)p;  p += 131072;
    short* qh    = (short*)p;  p += 4194304;
    short* kh    = (short*)p;  p += 4194304;
    short* vt    = (short*)p;  p += 4194304;
    short* biasM = (short*)p;  p += 16777216;
    float* out   = (float*)d_out;

    // 1) CPB MLP -> fp32 table [8][3969] (single launch, no atomics)
    cpb_kernel<<<63, 256, 0, stream>>>(rct, fc1w, fc1b, fc2w, fc2b, tblf);

    // 2) fragment-ordered bf16 bias, log2e folded (batch-independent)
    bias_mat<<<512, 256, 0, stream>>>(tblf, rpi, biasM);

    // 3) x / qkv_w / proj_w -> swizzled fp16
    split_kernel<<<1152, 256, 0, stream>>>(x, xh, qkvw, wqh, projw, wph);

    // 4) QKV GEMM (fp16 1-pass) + fused l2norm/scale + V transpose
    dim3 g1(768/64, 8192/128);
    gemm_mfma<1><<<g1, 256, 0, stream>>>(xh, wqh, qkvb, nullptr,
                                         qh, kh, vt, qe, temp, 768);

    // 5) MFMA attention (fp16 QK^T, exp2 domain, global-direct K/V) -> fp16 y
    attn_mfma<<<1024, 256, 0, stream>>>(qh, kh, vt, biasM, xh);

    // 6) output projection (fp16 1-pass) -> d_out (fp32)
    dim3 g2(256/64, 8192/128);
    gemm_mfma<0><<<g2, 256, 0, stream>>>(xh, wph, projb, out,
                                         nullptr, nullptr, nullptr,
                                         nullptr, nullptr, 256);
}

// Round 9
// 161.175 us; speedup vs baseline: 1.0237x; 1.0237x over previous
//
#include <hip/hip_runtime.h>
#include <hip/hip_bf16.h>
#include <cstddef>
#include <cstdint>

typedef float v4f __attribute__((ext_vector_type(4)));
typedef short v8s __attribute__((ext_vector_type(8)));
typedef _Float16 v8h __attribute__((ext_vector_type(8)));

__device__ __forceinline__ uint32_t fbits(float x){ uint32_t u; __builtin_memcpy(&u,&x,4); return u; }
__device__ __forceinline__ float ffrom(uint32_t u){ float f; __builtin_memcpy(&f,&u,4); return f; }
// round-half-up bf16
__device__ __forceinline__ short bf_rh(float x){ return (short)((fbits(x)+0x8000u)>>16); }
__device__ __forceinline__ uint32_t pack_bf_rh(float a, float b){
    uint32_t ua = fbits(a)+0x8000u, ub = fbits(b)+0x8000u;
#if __has_builtin(__builtin_amdgcn_perm)
    return __builtin_amdgcn_perm(ub, ua, 0x07060302u);
#else
    return (ua>>16) | (ub & 0xFFFF0000u);
#endif
}
// fp16 (RNE) stored in a short
__device__ __forceinline__ short f2h(float x){ _Float16 h = (_Float16)x; short s; __builtin_memcpy(&s,&h,2); return s; }
#if __has_builtin(__builtin_amdgcn_exp2f)
#define EXP2(x) __builtin_amdgcn_exp2f(x)
#else
#define EXP2(x) exp2f(x)
#endif

__device__ __forceinline__ void gld16(const void* g, void* l) {
    __builtin_amdgcn_global_load_lds(
        (const __attribute__((address_space(1))) unsigned int*)g,
        (__attribute__((address_space(3))) unsigned int*)l, 16, 0, 0);
}
#define MFMA(a,b,c)  __builtin_amdgcn_mfma_f32_16x16x32_bf16((a),(b),(c),0,0,0)
#define MFMAH(a,b,c) __builtin_amdgcn_mfma_f32_16x16x32_f16((a),(b),(c),0,0,0)

#define LOG2E 1.4426950408889634f

// ---------------------------------------------------------------------------
// CPB MLP, single launch, no atomics: 63 blocks x 63 rows; 4 threads per row
// split the 512 hidden dim, shuffle-reduce partials.
// ---------------------------------------------------------------------------
__global__ __launch_bounds__(256)
void cpb_kernel(const float* __restrict__ rct,
                const float* __restrict__ fc1w, const float* __restrict__ fc1b,
                const float* __restrict__ fc2w, const float* __restrict__ fc2b,
                float* __restrict__ table)
{
    __shared__ float s1[1024];
    __shared__ float sb[512];
    __shared__ float s2[4096];
    int tid = threadIdx.x;
    for (int i = tid; i < 1024; i += 256) s1[i] = fc1w[i];
    for (int i = tid; i < 512;  i += 256) sb[i] = fc1b[i];
    for (int i = tid; i < 4096; i += 256) s2[i] = fc2w[i];
    __syncthreads();
    int rl = tid >> 2, jp = tid & 3;
    bool ok = rl < 63;
    int r = blockIdx.x * 63 + rl;
    float c0 = ok ? rct[2*r]   : 0.f;
    float c1 = ok ? rct[2*r+1] : 0.f;
    float a[8] = {0,0,0,0,0,0,0,0};
    int j0 = jp * 128;
    #pragma unroll 4
    for (int j = j0; j < j0 + 128; ++j) {
        float hv = fmaxf(c0*s1[2*j] + c1*s1[2*j+1] + sb[j], 0.0f);
        #pragma unroll
        for (int hh = 0; hh < 8; ++hh) a[hh] += hv * s2[hh*512 + j];
    }
    #pragma unroll
    for (int hh = 0; hh < 8; ++hh) {
        a[hh] += __shfl_xor(a[hh], 1);
        a[hh] += __shfl_xor(a[hh], 2);
    }
    if (ok && jp == 0) {
        #pragma unroll
        for (int hh = 0; hh < 8; ++hh) table[hh*3969 + r] = a[hh] + fc2b[hh];
    }
}

// ---------------------------------------------------------------------------
// Materialize relative-position bias as bf16, scaled by log2(e), in MFMA
// C-fragment order matching the permuted K staging (key kt*64 + 4t + g).
// Layout: [h][q16(64)][kt(16)][g(4)][lane(64)][4 shorts] = 16 MB.
// ---------------------------------------------------------------------------
__global__ __launch_bounds__(256)
void bias_mat(const float* __restrict__ tblf, const int* __restrict__ rpi,
              short* __restrict__ biasM)
{
    __shared__ float tb[3969];
    int h   = blockIdx.x >> 6;
    int q16 = blockIdx.x & 63;
    int tid = threadIdx.x;
    int w = tid >> 6, lane = tid & 63, t = lane & 15, quad = lane >> 4;
    for (int i = tid; i < 3969; i += 256) tb[i] = tblf[h*3969 + i] * LOG2E;
    __syncthreads();
    int row0 = q16*16 + quad*4;
    #pragma unroll 1
    for (int kk = 0; kk < 4; ++kk) {
        int kt = w*4 + kk;
        #pragma unroll
        for (int g = 0; g < 4; ++g) {
            float o[4];
            #pragma unroll
            for (int r = 0; r < 4; ++r)
                o[r] = tb[rpi[(size_t)(row0 + r)*1024 + kt*64 + 4*t + g]];
            uint2 pk;
            pk.x = pack_bf_rh(o[0], o[1]);
            pk.y = pack_bf_rh(o[2], o[3]);
            size_t base = ((((size_t)(h*64 + q16)*16 + kt)*4 + g)*64 + lane)*4;
            *(uint2*)(biasM + base) = pk;
        }
    }
}

// ---------------------------------------------------------------------------
// fp32 -> fp16, 16B-chunk-swizzled: chunk c of row m stored at chunk
// (c ^ (m&7)) within its 64-elem K-tile. Inner dim K=256.
// ---------------------------------------------------------------------------
__global__ __launch_bounds__(256)
void split_kernel(const float* __restrict__ x,  short* __restrict__ xh,
                  const float* __restrict__ wq, short* __restrict__ wqh,
                  const float* __restrict__ wp, short* __restrict__ wph)
{
    int bid = blockIdx.x;
    const float* src; short* dh; int base8;
    if (bid < 1024)      { src = x;  dh = xh;  base8 = bid * 256; }
    else if (bid < 1120) { src = wq; dh = wqh; base8 = (bid-1024) * 256; }
    else                 { src = wp; dh = wph; base8 = (bid-1120) * 256; }
    int e0 = (base8 + (int)threadIdx.x) * 8;
    int m  = e0 >> 8;
    int k  = e0 & 255;
    int kt = k >> 6, c = (k >> 3) & 7;
    float4 f0 = *(const float4*)(src + e0);
    float4 f1 = *(const float4*)(src + e0 + 4);
    float v[8] = {f0.x,f0.y,f0.z,f0.w,f1.x,f1.y,f1.z,f1.w};
    v8s hi;
    #pragma unroll
    for (int j = 0; j < 8; ++j) hi[j] = f2h(v[j]);
    int dst = m*256 + kt*64 + ((c ^ (m & 7)) << 3);
    *(v8s*)&dh[dst] = hi;
}

// ---------------------------------------------------------------------------
// fp16 1-pass MFMA GEMM: C = A(MxK=256) * W(NxK=256)^T + bias.
// TM=128, TN=64, BK=128 (two 64-tile LDS buffers staged per iteration ->
// half the barrier/vmcnt-drain count of BK=64). 256 threads = 4 waves.
// MODE 0: plain fp32 C [M][N] (proj).
// MODE 1 (qkv): q: l2norm + qe + softplus(temp)*10, fp16 plain layout;
//   k: l2norm, fp16 KEY-PERMUTED within 64-tiles + chunk-swizzled;
//   v: bf16 transposed to vt[bh][32][1024] (chunk-swizzled) via LDS.
// ---------------------------------------------------------------------------
template<int MODE>
__global__ __launch_bounds__(256)
void gemm_mfma(const short* __restrict__ Ah_g, const short* __restrict__ Wh_g,
               const float* __restrict__ bias, float* __restrict__ C,
               short* __restrict__ qh, short* __restrict__ kh,
               short* __restrict__ vt,
               const float* __restrict__ qe, const float* __restrict__ temp,
               int N)
{
    __shared__ __align__(16) char smem[49152];
    short* A0 = (short*)smem;          // [128][64] fp16, k-tile even
    short* A1 = A0 + 128*64;           // [128][64] fp16, k-tile odd
    short* W0 = A1 + 128*64;           // [64][64]
    short* W1 = W0 + 64*64;

    int tid  = threadIdx.x;
    int w    = tid >> 6;
    int lane = tid & 63;
    int t    = lane & 15;
    int quad = lane >> 4;
    int m0 = blockIdx.y * 128, n0 = blockIdx.x * 64;
    int Mw = (w >> 1) * 64, Nw = (w & 1) * 32;

    v4f acc[4][2];
    #pragma unroll
    for (int mt = 0; mt < 4; ++mt)
        #pragma unroll
        for (int nt = 0; nt < 2; ++nt) acc[mt][nt] = (v4f){0,0,0,0};

    int lr8 = lane >> 3, lc8 = lane & 7;
    #pragma unroll 1
    for (int kt2 = 0; kt2 < 2; ++kt2) {
        __syncthreads();
        #pragma unroll
        for (int half = 0; half < 2; ++half) {
            int kt = kt2*2 + half;
            short* Ad = half ? A1 : A0;
            short* Wd = half ? W1 : W0;
            #pragma unroll
            for (int i = 0; i < 4; ++i) {
                size_t grow = (size_t)(m0 + w*32 + i*8 + lr8) * 256 + kt*64 + lc8*8;
                gld16(Ah_g + grow, Ad + (w*32 + i*8) * 64);
            }
            #pragma unroll
            for (int i = 0; i < 2; ++i) {
                size_t grow = (size_t)(n0 + w*16 + i*8 + lr8) * 256 + kt*64 + lc8*8;
                gld16(Wh_g + grow, Wd + (w*16 + i*8) * 64);
            }
        }
        __syncthreads();
        #pragma unroll
        for (int half = 0; half < 2; ++half) {
            const short* As = half ? A1 : A0;
            const short* Ws = half ? W1 : W0;
            #pragma unroll
            for (int kk = 0; kk < 2; ++kk) {
                int cp = ((kk*4 + quad) ^ (t & 7)) << 3;
                v8h bh8[2];
                #pragma unroll
                for (int nt = 0; nt < 2; ++nt)
                    bh8[nt] = *(const v8h*)&Ws[(Nw + nt*16 + t)*64 + cp];
                #pragma unroll
                for (int mt = 0; mt < 4; ++mt) {
                    v8h ah = *(const v8h*)&As[(Mw + mt*16 + t)*64 + cp];
                    #pragma unroll
                    for (int nt = 0; nt < 2; ++nt)
                        acc[mt][nt] = MFMAH(ah, bh8[nt], acc[mt][nt]);
                }
            }
        }
    }

    // bias
    #pragma unroll
    for (int nt = 0; nt < 2; ++nt) {
        float bv = bias[n0 + Nw + nt*16 + t];
        #pragma unroll
        for (int mt = 0; mt < 4; ++mt)
            #pragma unroll
            for (int r = 0; r < 4; ++r) acc[mt][nt][r] += bv;
    }

    if (MODE == 0) {
        #pragma unroll
        for (int mt = 0; mt < 4; ++mt)
            #pragma unroll
            for (int r = 0; r < 4; ++r) {
                int m = m0 + Mw + mt*16 + quad*4 + r;
                #pragma unroll
                for (int nt = 0; nt < 2; ++nt)
                    C[(size_t)m * N + n0 + Nw + nt*16 + t] = acc[mt][nt][r];
            }
    } else {
        int which = n0 >> 8;
        if (which < 2) {
            int head = ((n0 + Nw) >> 5) & 7;
            float scale = 0.f;
            if (which == 0)
                scale = log1pf(__expf(temp[head])) * 10.0f;  // softplus*ln(1024)*log2e
            #pragma unroll
            for (int mt = 0; mt < 4; ++mt)
                #pragma unroll
                for (int r = 0; r < 4; ++r) {
                    float a0 = acc[mt][0][r], a1 = acc[mt][1][r];
                    float s = a0*a0 + a1*a1;
                    s += __shfl_xor(s, 1); s += __shfl_xor(s, 2);
                    s += __shfl_xor(s, 4); s += __shfl_xor(s, 8);
                    float inv = 1.0f / fmaxf(sqrtf(s), 1e-12f);
                    int m = m0 + Mw + mt*16 + quad*4 + r;
                    int b = m >> 10, nrow = m & 1023;
                    if (which == 0) {
                        size_t rowoff = (((size_t)b*8 + head)*1024 + nrow) * 32;
                        #pragma unroll
                        for (int nt = 0; nt < 2; ++nt) {
                            int d = nt*16 + t;
                            float val = (acc[mt][nt][r] * inv + qe[head*32 + d]) * scale;
                            qh[rowoff + d] = f2h(val);
                        }
                    } else {
                        int kk = nrow & 63;
                        int p  = (kk & 3)*16 + (kk >> 2);
                        int prow = (nrow & ~63) | p;
                        int swk = (kk >> 3) & 3;
                        size_t rowoff = (((size_t)b*8 + head)*1024 + prow) * 32;
                        #pragma unroll
                        for (int nt = 0; nt < 2; ++nt) {
                            int d = nt*16 + t;
                            int dpos = (((d >> 3) ^ swk) << 3) | (d & 7);
                            kh[rowoff + dpos] = f2h(acc[mt][nt][r] * inv);
                        }
                    }
                }
        } else {
            // v: transpose via LDS, write vt[bh][dim][key] bf16, tile-swizzled
            __syncthreads();
            short* VT = (short*)smem;        // [64][136]
            #pragma unroll
            for (int mt = 0; mt < 4; ++mt)
                #pragma unroll
                for (int nt = 0; nt < 2; ++nt) {
                    int cl = Nw + nt*16 + t;
                    #pragma unroll
                    for (int r = 0; r < 4; ++r) {
                        int rl = Mw + mt*16 + quad*4 + r;
                        VT[cl*136 + rl] = bf_rh(acc[mt][nt][r]);
                    }
                }
            __syncthreads();
            int b = m0 >> 10;
            int keybase = m0 & 1023;
            int headbase = ((n0 - 512) >> 5) & 7;
            int cl = tid >> 2;
            int dim = cl & 31;
            int hd  = headbase + (cl >> 5);
            size_t obase = (((size_t)b*8 + hd)*32 + dim) * 1024 + keybase;
            #pragma unroll
            for (int p = 0; p < 4; ++p) {
                int ci  = (tid & 3) * 4 + p;
                int ktl = ci >> 3, c = ci & 7;
                v8s val = *(const v8s*)&VT[cl*136 + ktl*64 + c*8];
                *(v8s*)&vt[obase + ktl*64 + ((c ^ (dim & 7)) << 3)] = val;
            }
        }
    }
}

// ---------------------------------------------------------------------------
// MFMA flash attention, exp2 domain, fp16 QK^T (1 MFMA per 16x16 S tile),
// bf16 PV (P can reach 2^46 — needs bf16 range). Double-buffered K/V LDS,
// bf16 bias as MFMA C-init (register-pipelined), key-permuted K so P stores
// are packed b64 writes. Output: swizzled fp16 y for the 1-pass proj GEMM.
// ---------------------------------------------------------------------------
__global__ __launch_bounds__(256)
void attn_mfma(const short* __restrict__ qh, const short* __restrict__ kh,
               const short* __restrict__ vt,  const short* __restrict__ biasM,
               short* __restrict__ yh)
{
    __shared__ __align__(16) short Kh_s[2][2048];   // [64][32] fp16
    __shared__ __align__(16) short Vt_s[2][2048];   // [32][64] bf16
    __shared__ __align__(16) short Ps[4][16][68];   // per-wave P (bf16, cols=keys)

    int bh  = blockIdx.x >> 4;
    int qt  = blockIdx.x & 15;
    int h   = bh & 7;
    int b   = bh >> 3;
    int tid = threadIdx.x;
    int w    = tid >> 6;
    int lane = tid & 63;
    int t    = lane & 15;
    int quad = lane >> 4;

    size_t qoff = ((size_t)bh*1024 + qt*64 + w*16 + t) * 32 + quad*8;
    v8h qf = *(const v8h*)(qh + qoff);

    v4f Oacc[2] = {{0,0,0,0},{0,0,0,0}};
    float lsum[4] = {0,0,0,0};

    size_t kgbase = (size_t)bh * 32768;
    const short* bmb = biasM + ((size_t)(h*64 + qt*4 + w) * 16) * 1024 + lane*4;
    int qrow0 = qt*64 + w*16 + quad*4;
    int swzS = (quad ^ ((t >> 1) & 3)) << 3;
    int lr8 = lane >> 3, lc8 = lane & 7;

    // stage tile 0 into buffer 0
    gld16(kh + kgbase + w*512 + lane*8, &Kh_s[0][w*512]);
    gld16(vt + kgbase + (size_t)(w*8 + lr8)*1024 + lc8*8, &Vt_s[0][w*512]);
    uint2 curb[4];
    #pragma unroll
    for (int g = 0; g < 4; ++g) curb[g] = *(const uint2*)(bmb + g*256);

    #pragma unroll 1
    for (int kt = 0; kt < 16; ++kt) {
        int cur = kt & 1;
        __syncthreads();
        uint2 nxtb[4];
        if (kt < 15) {
            int nkt = kt + 1, nb = cur ^ 1;
            gld16(kh + kgbase + (size_t)nkt*2048 + w*512 + lane*8, &Kh_s[nb][w*512]);
            gld16(vt + kgbase + (size_t)(w*8 + lr8)*1024 + nkt*64 + lc8*8, &Vt_s[nb][w*512]);
            const short* bp = bmb + (size_t)nkt*1024;
            #pragma unroll
            for (int g = 0; g < 4; ++g) nxtb[g] = *(const uint2*)(bp + g*256);
        }

        // S = bias + Q K^T (fp16, 1 pass), exp2 domain
        v4f S[4];
        #pragma unroll
        for (int g = 0; g < 4; ++g) {
            v8h kb = *(const v8h*)&Kh_s[cur][(g*16 + t)*32 + swzS];
            v4f c;
            c[0] = ffrom(curb[g].x << 16);
            c[1] = ffrom(curb[g].x & 0xFFFF0000u);
            c[2] = ffrom(curb[g].y << 16);
            c[3] = ffrom(curb[g].y & 0xFFFF0000u);
            S[g] = MFMAH(qf, kb, c);
        }

        // p = exp2(S); P cols are contiguous actual keys 4t+g -> packed b64
        #pragma unroll
        for (int r = 0; r < 4; ++r) {
            float p0 = EXP2(S[0][r]);
            float p1 = EXP2(S[1][r]);
            float p2 = EXP2(S[2][r]);
            float p3 = EXP2(S[3][r]);
            lsum[r] += (p0 + p1) + (p2 + p3);
            uint2 pk;
            pk.x = pack_bf_rh(p0, p1);
            pk.y = pack_bf_rh(p2, p3);
            *(uint2*)&Ps[w][quad*4 + r][t*4] = pk;
        }

        // O += P V (same-wave LDS dependency, no barrier)
        #pragma unroll
        for (int ks = 0; ks < 2; ++ks) {
            v8s pf = *(const v8s*)&Ps[w][t][ks*32 + quad*8];
            int vsw = ((ks*4 + quad) ^ (t & 7)) << 3;
            #pragma unroll
            for (int g = 0; g < 2; ++g) {
                v8s vf = *(const v8s*)&Vt_s[cur][(g*16 + t)*64 + vsw];
                Oacc[g] = MFMA(pf, vf, Oacc[g]);
            }
        }
        #pragma unroll
        for (int g = 0; g < 4; ++g) curb[g] = nxtb[g];
    }

    // epilogue: reduce l, normalize, write swizzled fp16 y
    #pragma unroll
    for (int r = 0; r < 4; ++r) {
        float l = lsum[r];
        l += __shfl_xor(l, 1); l += __shfl_xor(l, 2);
        l += __shfl_xor(l, 4); l += __shfl_xor(l, 8);
        float inv = 1.0f / l;
        int qrow = qrow0 + r;
        int m = b*1024 + qrow;
        size_t mbase = (size_t)m * 256;
        int mk = m & 7;
        #pragma unroll
        for (int g = 0; g < 2; ++g) {
            float o = Oacc[g][r] * inv;
            int c = h*4 + g*2 + (t >> 3);
            int chp = ((c ^ mk) << 3) | (t & 7);
            yh[mbase + chp] = f2h(o);
        }
    }
}

// ---------------------------------------------------------------------------
extern "C" void kernel_launch(void* const* d_in, const int* in_sizes, int n_in,
                              void* d_out, int out_size, void* d_ws, size_t ws_size,
                              hipStream_t stream)
{
    const float* x     = (const float*)d_in[0];
    const int*   rpi   = (const int*)d_in[3];
    const float* rct   = (const float*)d_in[4];
    const float* qkvw  = (const float*)d_in[5];
    const float* qkvb  = (const float*)d_in[6];
    const float* qe    = (const float*)d_in[7];
    const float* temp  = (const float*)d_in[8];
    const float* projw = (const float*)d_in[9];
    const float* projb = (const float*)d_in[10];
    const float* fc1w  = (const float*)d_in[11];
    const float* fc1b  = (const float*)d_in[12];
    const float* fc2w  = (const float*)d_in[13];
    const float* fc2b  = (const float*)d_in[14];

    char* p = (char*)d_ws;
    float* tblf  = (float*)p;  p += 131072;
    short* xh    = (short*)p;  p += 4194304;   // reused as y (fp16) after attn
    short* wqh   = (short*)p;  p += 393216;
    short* wph   = (short*)p;  p += 131072;
    short* qh    = (short*)p;  p += 4194304;
    short* kh    = (short*)p;  p += 4194304;
    short* vt    = (short*)p;  p += 4194304;
    short* biasM = (short*)p;  p += 16777216;
    float* out   = (float*)d_out;

    // 1) CPB MLP -> fp32 table [8][3969] (single launch, no atomics)
    cpb_kernel<<<63, 256, 0, stream>>>(rct, fc1w, fc1b, fc2w, fc2b, tblf);

    // 2) fragment-ordered bf16 bias, log2e folded (batch-independent)
    bias_mat<<<512, 256, 0, stream>>>(tblf, rpi, biasM);

    // 3) x / qkv_w / proj_w -> swizzled fp16
    split_kernel<<<1152, 256, 0, stream>>>(x, xh, qkvw, wqh, projw, wph);

    // 4) QKV GEMM (fp16 1-pass, BK=128) + fused l2norm/scale + V transpose
    dim3 g1(768/64, 8192/128);
    gemm_mfma<1><<<g1, 256, 0, stream>>>(xh, wqh, qkvb, nullptr,
                                         qh, kh, vt, qe, temp, 768);

    // 5) MFMA attention (fp16 QK^T, exp2 domain, LDS-staged K/V) -> fp16 y
    attn_mfma<<<1024, 256, 0, stream>>>(qh, kh, vt, biasM, xh);

    // 6) output projection (fp16 1-pass, BK=128) -> d_out (fp32)
    dim3 g2(256/64, 8192/128);
    gemm_mfma<0><<<g2, 256, 0, stream>>>(xh, wph, projb, out,
                                         nullptr, nullptr, nullptr,
                                         nullptr, nullptr, 256);
}

// Round 10
// 152.219 us; speedup vs baseline: 1.0840x; 1.0588x over previous
//
#include <hip/hip_runtime.h>
#include <hip/hip_bf16.h>
#include <cstddef>
#include <cstdint>

typedef float v4f __attribute__((ext_vector_type(4)));
typedef short v8s __attribute__((ext_vector_type(8)));
typedef _Float16 v8h __attribute__((ext_vector_type(8)));

__device__ __forceinline__ uint32_t fbits(float x){ uint32_t u; __builtin_memcpy(&u,&x,4); return u; }
__device__ __forceinline__ float ffrom(uint32_t u){ float f; __builtin_memcpy(&f,&u,4); return f; }
// round-half-up bf16
__device__ __forceinline__ short bf_rh(float x){ return (short)((fbits(x)+0x8000u)>>16); }
__device__ __forceinline__ uint32_t pack_bf_rh(float a, float b){
    uint32_t ua = fbits(a)+0x8000u, ub = fbits(b)+0x8000u;
#if __has_builtin(__builtin_amdgcn_perm)
    return __builtin_amdgcn_perm(ub, ua, 0x07060302u);
#else
    return (ua>>16) | (ub & 0xFFFF0000u);
#endif
}
// fp16 (RNE) stored in a short
__device__ __forceinline__ short f2h(float x){ _Float16 h = (_Float16)x; short s; __builtin_memcpy(&s,&h,2); return s; }
#if __has_builtin(__builtin_amdgcn_exp2f)
#define EXP2(x) __builtin_amdgcn_exp2f(x)
#else
#define EXP2(x) exp2f(x)
#endif

__device__ __forceinline__ void gld16(const void* g, void* l) {
    __builtin_amdgcn_global_load_lds(
        (const __attribute__((address_space(1))) unsigned int*)g,
        (__attribute__((address_space(3))) unsigned int*)l, 16, 0, 0);
}
#define MFMA(a,b,c)  __builtin_amdgcn_mfma_f32_16x16x32_bf16((a),(b),(c),0,0,0)
#define MFMAH(a,b,c) __builtin_amdgcn_mfma_f32_16x16x32_f16((a),(b),(c),0,0,0)

#define LOG2E 1.4426950408889634f

// ---------------------------------------------------------------------------
// PREP (merged): blocks 0..1151 convert x/qkv_w/proj_w fp32 -> fp16 with the
// 16B-chunk swizzle (chunk c of row m at c^(m&7) within its 64-elem K-tile);
// blocks 1152..1214 run the CPB MLP (63 rows each, 4 threads/row, shuffle
// reduce) -> fp32 table [8][3969]. Independent work, one launch.
// ---------------------------------------------------------------------------
__global__ __launch_bounds__(256)
void prep_kernel(const float* __restrict__ x,  short* __restrict__ xh,
                 const float* __restrict__ wq, short* __restrict__ wqh,
                 const float* __restrict__ wp, short* __restrict__ wph,
                 const float* __restrict__ rct,
                 const float* __restrict__ fc1w, const float* __restrict__ fc1b,
                 const float* __restrict__ fc2w, const float* __restrict__ fc2b,
                 float* __restrict__ table)
{
    __shared__ float s1[1024];
    __shared__ float sb[512];
    __shared__ float s2[4096];
    int bid = blockIdx.x;
    int tid = threadIdx.x;
    if (bid < 1152) {
        const float* src; short* dh; int base8;
        if (bid < 1024)      { src = x;  dh = xh;  base8 = bid * 256; }
        else if (bid < 1120) { src = wq; dh = wqh; base8 = (bid-1024) * 256; }
        else                 { src = wp; dh = wph; base8 = (bid-1120) * 256; }
        int e0 = (base8 + tid) * 8;
        int m  = e0 >> 8;
        int k  = e0 & 255;
        int kt = k >> 6, c = (k >> 3) & 7;
        float4 f0 = *(const float4*)(src + e0);
        float4 f1 = *(const float4*)(src + e0 + 4);
        float v[8] = {f0.x,f0.y,f0.z,f0.w,f1.x,f1.y,f1.z,f1.w};
        v8s hi;
        #pragma unroll
        for (int j = 0; j < 8; ++j) hi[j] = f2h(v[j]);
        int dst = m*256 + kt*64 + ((c ^ (m & 7)) << 3);
        *(v8s*)&dh[dst] = hi;
    } else {
        int cbid = bid - 1152;
        for (int i = tid; i < 1024; i += 256) s1[i] = fc1w[i];
        for (int i = tid; i < 512;  i += 256) sb[i] = fc1b[i];
        for (int i = tid; i < 4096; i += 256) s2[i] = fc2w[i];
        __syncthreads();
        int rl = tid >> 2, jp = tid & 3;
        bool ok = rl < 63;
        int r = cbid * 63 + rl;
        float c0 = ok ? rct[2*r]   : 0.f;
        float c1 = ok ? rct[2*r+1] : 0.f;
        float a[8] = {0,0,0,0,0,0,0,0};
        int j0 = jp * 128;
        #pragma unroll 4
        for (int j = j0; j < j0 + 128; ++j) {
            float hv = fmaxf(c0*s1[2*j] + c1*s1[2*j+1] + sb[j], 0.0f);
            #pragma unroll
            for (int hh = 0; hh < 8; ++hh) a[hh] += hv * s2[hh*512 + j];
        }
        #pragma unroll
        for (int hh = 0; hh < 8; ++hh) {
            a[hh] += __shfl_xor(a[hh], 1);
            a[hh] += __shfl_xor(a[hh], 2);
        }
        if (ok && jp == 0) {
            #pragma unroll
            for (int hh = 0; hh < 8; ++hh) table[hh*3969 + r] = a[hh] + fc2b[hh];
        }
    }
}

// ---------------------------------------------------------------------------
// QKV GEMM + BIAS MATERIALIZATION (merged, independent halves):
// blocks 0..767: fp16 1-pass MFMA GEMM qkv = x @ qkv_w^T + b, TM=128 TN=64
//   BK=128 (double-staged), fused epilogue:
//   q: l2norm + qe + softplus(temp)*10 (log2e folded), fp16 plain layout;
//   k: l2norm, fp16 KEY-PERMUTED within 64-tiles + chunk-swizzled;
//   v: bf16 transposed to vt[bh][32][1024] (chunk-swizzled) via LDS.
// blocks 768..1279: bias_mat — bf16 bias scaled by log2(e) in MFMA C-frag
//   order matching permuted keys (key kt*64 + 4t + g), 16 MB.
// ---------------------------------------------------------------------------
__global__ __launch_bounds__(256)
void qkv_bias_kernel(const short* __restrict__ xh, const short* __restrict__ wqh,
                     const float* __restrict__ qkvb,
                     short* __restrict__ qh, short* __restrict__ kh,
                     short* __restrict__ vt,
                     const float* __restrict__ qe, const float* __restrict__ temp,
                     const float* __restrict__ tblf, const int* __restrict__ rpi,
                     short* __restrict__ biasM)
{
    __shared__ __align__(16) char smem[49152];
    int bid  = blockIdx.x;
    int tid  = threadIdx.x;
    int w    = tid >> 6;
    int lane = tid & 63;
    int t    = lane & 15;
    int quad = lane >> 4;

    if (bid < 768) {
        short* A0 = (short*)smem;          // [128][64] fp16, k-tile even
        short* A1 = A0 + 128*64;
        short* W0 = A1 + 128*64;           // [64][64]
        short* W1 = W0 + 64*64;
        int n0 = (bid % 12) * 64, m0 = (bid / 12) * 128;
        int Mw = (w >> 1) * 64, Nw = (w & 1) * 32;

        v4f acc[4][2];
        #pragma unroll
        for (int mt = 0; mt < 4; ++mt)
            #pragma unroll
            for (int nt = 0; nt < 2; ++nt) acc[mt][nt] = (v4f){0,0,0,0};

        int lr8 = lane >> 3, lc8 = lane & 7;
        #pragma unroll 1
        for (int kt2 = 0; kt2 < 2; ++kt2) {
            __syncthreads();
            #pragma unroll
            for (int half = 0; half < 2; ++half) {
                int kt = kt2*2 + half;
                short* Ad = half ? A1 : A0;
                short* Wd = half ? W1 : W0;
                #pragma unroll
                for (int i = 0; i < 4; ++i) {
                    size_t grow = (size_t)(m0 + w*32 + i*8 + lr8) * 256 + kt*64 + lc8*8;
                    gld16(xh + grow, Ad + (w*32 + i*8) * 64);
                }
                #pragma unroll
                for (int i = 0; i < 2; ++i) {
                    size_t grow = (size_t)(n0 + w*16 + i*8 + lr8) * 256 + kt*64 + lc8*8;
                    gld16(wqh + grow, Wd + (w*16 + i*8) * 64);
                }
            }
            __syncthreads();
            #pragma unroll
            for (int half = 0; half < 2; ++half) {
                const short* As = half ? A1 : A0;
                const short* Ws = half ? W1 : W0;
                #pragma unroll
                for (int kk = 0; kk < 2; ++kk) {
                    int cp = ((kk*4 + quad) ^ (t & 7)) << 3;
                    v8h bh8[2];
                    #pragma unroll
                    for (int nt = 0; nt < 2; ++nt)
                        bh8[nt] = *(const v8h*)&Ws[(Nw + nt*16 + t)*64 + cp];
                    #pragma unroll
                    for (int mt = 0; mt < 4; ++mt) {
                        v8h ah = *(const v8h*)&As[(Mw + mt*16 + t)*64 + cp];
                        #pragma unroll
                        for (int nt = 0; nt < 2; ++nt)
                            acc[mt][nt] = MFMAH(ah, bh8[nt], acc[mt][nt]);
                    }
                }
            }
        }

        // bias
        #pragma unroll
        for (int nt = 0; nt < 2; ++nt) {
            float bv = qkvb[n0 + Nw + nt*16 + t];
            #pragma unroll
            for (int mt = 0; mt < 4; ++mt)
                #pragma unroll
                for (int r = 0; r < 4; ++r) acc[mt][nt][r] += bv;
        }

        int which = n0 >> 8;
        if (which < 2) {
            int head = ((n0 + Nw) >> 5) & 7;
            float scale = 0.f;
            if (which == 0)
                scale = log1pf(__expf(temp[head])) * 10.0f;  // softplus*ln(1024)*log2e
            #pragma unroll
            for (int mt = 0; mt < 4; ++mt)
                #pragma unroll
                for (int r = 0; r < 4; ++r) {
                    float a0 = acc[mt][0][r], a1 = acc[mt][1][r];
                    float s = a0*a0 + a1*a1;
                    s += __shfl_xor(s, 1); s += __shfl_xor(s, 2);
                    s += __shfl_xor(s, 4); s += __shfl_xor(s, 8);
                    float inv = 1.0f / fmaxf(sqrtf(s), 1e-12f);
                    int m = m0 + Mw + mt*16 + quad*4 + r;
                    int b = m >> 10, nrow = m & 1023;
                    if (which == 0) {
                        size_t rowoff = (((size_t)b*8 + head)*1024 + nrow) * 32;
                        #pragma unroll
                        for (int nt = 0; nt < 2; ++nt) {
                            int d = nt*16 + t;
                            float val = (acc[mt][nt][r] * inv + qe[head*32 + d]) * scale;
                            qh[rowoff + d] = f2h(val);
                        }
                    } else {
                        int kk = nrow & 63;
                        int p  = (kk & 3)*16 + (kk >> 2);
                        int prow = (nrow & ~63) | p;
                        int swk = (kk >> 3) & 3;
                        size_t rowoff = (((size_t)b*8 + head)*1024 + prow) * 32;
                        #pragma unroll
                        for (int nt = 0; nt < 2; ++nt) {
                            int d = nt*16 + t;
                            int dpos = (((d >> 3) ^ swk) << 3) | (d & 7);
                            kh[rowoff + dpos] = f2h(acc[mt][nt][r] * inv);
                        }
                    }
                }
        } else {
            // v: transpose via LDS, write vt[bh][dim][key] bf16, tile-swizzled
            __syncthreads();
            short* VT = (short*)smem;        // [64][136]
            #pragma unroll
            for (int mt = 0; mt < 4; ++mt)
                #pragma unroll
                for (int nt = 0; nt < 2; ++nt) {
                    int cl = Nw + nt*16 + t;
                    #pragma unroll
                    for (int r = 0; r < 4; ++r) {
                        int rl = Mw + mt*16 + quad*4 + r;
                        VT[cl*136 + rl] = bf_rh(acc[mt][nt][r]);
                    }
                }
            __syncthreads();
            int b = m0 >> 10;
            int keybase = m0 & 1023;
            int headbase = ((n0 - 512) >> 5) & 7;
            int cl = tid >> 2;
            int dim = cl & 31;
            int hd  = headbase + (cl >> 5);
            size_t obase = (((size_t)b*8 + hd)*32 + dim) * 1024 + keybase;
            #pragma unroll
            for (int p = 0; p < 4; ++p) {
                int ci  = (tid & 3) * 4 + p;
                int ktl = ci >> 3, c = ci & 7;
                v8s val = *(const v8s*)&VT[cl*136 + ktl*64 + c*8];
                *(v8s*)&vt[obase + ktl*64 + ((c ^ (dim & 7)) << 3)] = val;
            }
        }
    } else {
        // ------- bias_mat half -------
        float* tb = (float*)smem;            // [3969]
        int b2  = bid - 768;
        int h   = b2 >> 6;
        int q16 = b2 & 63;
        for (int i = tid; i < 3969; i += 256) tb[i] = tblf[h*3969 + i] * LOG2E;
        __syncthreads();
        int row0 = q16*16 + quad*4;
        #pragma unroll 1
        for (int kk = 0; kk < 4; ++kk) {
            int kt = w*4 + kk;
            #pragma unroll
            for (int g = 0; g < 4; ++g) {
                float o[4];
                #pragma unroll
                for (int r = 0; r < 4; ++r)
                    o[r] = tb[rpi[(size_t)(row0 + r)*1024 + kt*64 + 4*t + g]];
                uint2 pk;
                pk.x = pack_bf_rh(o[0], o[1]);
                pk.y = pack_bf_rh(o[2], o[3]);
                size_t base = ((((size_t)(h*64 + q16)*16 + kt)*4 + g)*64 + lane)*4;
                *(uint2*)(biasM + base) = pk;
            }
        }
    }
}

// ---------------------------------------------------------------------------
// MFMA flash attention, exp2 domain, fp16 QK^T (1 MFMA per 16x16 S tile),
// bf16 PV (P can reach 2^46 — needs bf16 range). Double-buffered K/V LDS,
// bf16 bias as MFMA C-init (register-pipelined), key-permuted K so P stores
// are packed b64 writes. Output: swizzled fp16 y for the 1-pass proj GEMM.
// ---------------------------------------------------------------------------
__global__ __launch_bounds__(256)
void attn_mfma(const short* __restrict__ qh, const short* __restrict__ kh,
               const short* __restrict__ vt,  const short* __restrict__ biasM,
               short* __restrict__ yh)
{
    __shared__ __align__(16) short Kh_s[2][2048];   // [64][32] fp16
    __shared__ __align__(16) short Vt_s[2][2048];   // [32][64] bf16
    __shared__ __align__(16) short Ps[4][16][68];   // per-wave P (bf16, cols=keys)

    int bh  = blockIdx.x >> 4;
    int qt  = blockIdx.x & 15;
    int h   = bh & 7;
    int b   = bh >> 3;
    int tid = threadIdx.x;
    int w    = tid >> 6;
    int lane = tid & 63;
    int t    = lane & 15;
    int quad = lane >> 4;

    size_t qoff = ((size_t)bh*1024 + qt*64 + w*16 + t) * 32 + quad*8;
    v8h qf = *(const v8h*)(qh + qoff);

    v4f Oacc[2] = {{0,0,0,0},{0,0,0,0}};
    float lsum[4] = {0,0,0,0};

    size_t kgbase = (size_t)bh * 32768;
    const short* bmb = biasM + ((size_t)(h*64 + qt*4 + w) * 16) * 1024 + lane*4;
    int qrow0 = qt*64 + w*16 + quad*4;
    int swzS = (quad ^ ((t >> 1) & 3)) << 3;
    int lr8 = lane >> 3, lc8 = lane & 7;

    // stage tile 0 into buffer 0
    gld16(kh + kgbase + w*512 + lane*8, &Kh_s[0][w*512]);
    gld16(vt + kgbase + (size_t)(w*8 + lr8)*1024 + lc8*8, &Vt_s[0][w*512]);
    uint2 curb[4];
    #pragma unroll
    for (int g = 0; g < 4; ++g) curb[g] = *(const uint2*)(bmb + g*256);

    #pragma unroll 1
    for (int kt = 0; kt < 16; ++kt) {
        int cur = kt & 1;
        __syncthreads();
        uint2 nxtb[4];
        if (kt < 15) {
            int nkt = kt + 1, nb = cur ^ 1;
            gld16(kh + kgbase + (size_t)nkt*2048 + w*512 + lane*8, &Kh_s[nb][w*512]);
            gld16(vt + kgbase + (size_t)(w*8 + lr8)*1024 + nkt*64 + lc8*8, &Vt_s[nb][w*512]);
            const short* bp = bmb + (size_t)nkt*1024;
            #pragma unroll
            for (int g = 0; g < 4; ++g) nxtb[g] = *(const uint2*)(bp + g*256);
        }

        // S = bias + Q K^T (fp16, 1 pass), exp2 domain
        v4f S[4];
        #pragma unroll
        for (int g = 0; g < 4; ++g) {
            v8h kb = *(const v8h*)&Kh_s[cur][(g*16 + t)*32 + swzS];
            v4f c;
            c[0] = ffrom(curb[g].x << 16);
            c[1] = ffrom(curb[g].x & 0xFFFF0000u);
            c[2] = ffrom(curb[g].y << 16);
            c[3] = ffrom(curb[g].y & 0xFFFF0000u);
            S[g] = MFMAH(qf, kb, c);
        }

        // p = exp2(S); P cols are contiguous actual keys 4t+g -> packed b64
        #pragma unroll
        for (int r = 0; r < 4; ++r) {
            float p0 = EXP2(S[0][r]);
            float p1 = EXP2(S[1][r]);
            float p2 = EXP2(S[2][r]);
            float p3 = EXP2(S[3][r]);
            lsum[r] += (p0 + p1) + (p2 + p3);
            uint2 pk;
            pk.x = pack_bf_rh(p0, p1);
            pk.y = pack_bf_rh(p2, p3);
            *(uint2*)&Ps[w][quad*4 + r][t*4] = pk;
        }

        // O += P V (same-wave LDS dependency, no barrier)
        #pragma unroll
        for (int ks = 0; ks < 2; ++ks) {
            v8s pf = *(const v8s*)&Ps[w][t][ks*32 + quad*8];
            int vsw = ((ks*4 + quad) ^ (t & 7)) << 3;
            #pragma unroll
            for (int g = 0; g < 2; ++g) {
                v8s vf = *(const v8s*)&Vt_s[cur][(g*16 + t)*64 + vsw];
                Oacc[g] = MFMA(pf, vf, Oacc[g]);
            }
        }
        #pragma unroll
        for (int g = 0; g < 4; ++g) curb[g] = nxtb[g];
    }

    // epilogue: reduce l, normalize, write swizzled fp16 y
    #pragma unroll
    for (int r = 0; r < 4; ++r) {
        float l = lsum[r];
        l += __shfl_xor(l, 1); l += __shfl_xor(l, 2);
        l += __shfl_xor(l, 4); l += __shfl_xor(l, 8);
        float inv = 1.0f / l;
        int qrow = qrow0 + r;
        int m = b*1024 + qrow;
        size_t mbase = (size_t)m * 256;
        int mk = m & 7;
        #pragma unroll
        for (int g = 0; g < 2; ++g) {
            float o = Oacc[g][r] * inv;
            int c = h*4 + g*2 + (t >> 3);
            int chp = ((c ^ mk) << 3) | (t & 7);
            yh[mbase + chp] = f2h(o);
        }
    }
}

// ---------------------------------------------------------------------------
// Output projection: fp16 1-pass MFMA GEMM, TM=64 TN=64 (512 blocks ->
// 2 blocks/CU, 2 waves/SIMD vs 1 for TM=128), BK=128 double-staged.
// ---------------------------------------------------------------------------
__global__ __launch_bounds__(256)
void gemm_proj(const short* __restrict__ Ah_g, const short* __restrict__ Wh_g,
               const float* __restrict__ bias, float* __restrict__ C, int N)
{
    __shared__ __align__(16) short As[2][4096];   // [64][64] fp16 per buf
    __shared__ __align__(16) short Ws[2][4096];

    int tid  = threadIdx.x;
    int w    = tid >> 6;
    int lane = tid & 63;
    int t    = lane & 15;
    int quad = lane >> 4;
    int m0 = blockIdx.y * 64, n0 = blockIdx.x * 64;
    int Mw = (w >> 1) * 32, Nw = (w & 1) * 32;

    v4f acc[2][2];
    #pragma unroll
    for (int mt = 0; mt < 2; ++mt)
        #pragma unroll
        for (int nt = 0; nt < 2; ++nt) acc[mt][nt] = (v4f){0,0,0,0};

    int lr8 = lane >> 3, lc8 = lane & 7;
    #pragma unroll 1
    for (int kt2 = 0; kt2 < 2; ++kt2) {
        __syncthreads();
        #pragma unroll
        for (int half = 0; half < 2; ++half) {
            int kt = kt2*2 + half;
            #pragma unroll
            for (int i = 0; i < 2; ++i) {
                size_t grow = (size_t)(m0 + w*16 + i*8 + lr8) * 256 + kt*64 + lc8*8;
                gld16(Ah_g + grow, &As[half][(w*16 + i*8) * 64]);
            }
            #pragma unroll
            for (int i = 0; i < 2; ++i) {
                size_t grow = (size_t)(n0 + w*16 + i*8 + lr8) * 256 + kt*64 + lc8*8;
                gld16(Wh_g + grow, &Ws[half][(w*16 + i*8) * 64]);
            }
        }
        __syncthreads();
        #pragma unroll
        for (int half = 0; half < 2; ++half) {
            #pragma unroll
            for (int kk = 0; kk < 2; ++kk) {
                int cp = ((kk*4 + quad) ^ (t & 7)) << 3;
                v8h bh8[2];
                #pragma unroll
                for (int nt = 0; nt < 2; ++nt)
                    bh8[nt] = *(const v8h*)&Ws[half][(Nw + nt*16 + t)*64 + cp];
                #pragma unroll
                for (int mt = 0; mt < 2; ++mt) {
                    v8h ah = *(const v8h*)&As[half][(Mw + mt*16 + t)*64 + cp];
                    #pragma unroll
                    for (int nt = 0; nt < 2; ++nt)
                        acc[mt][nt] = MFMAH(ah, bh8[nt], acc[mt][nt]);
                }
            }
        }
    }

    #pragma unroll
    for (int nt = 0; nt < 2; ++nt) {
        float bv = bias[n0 + Nw + nt*16 + t];
        #pragma unroll
        for (int mt = 0; mt < 2; ++mt)
            #pragma unroll
            for (int r = 0; r < 4; ++r) acc[mt][nt][r] += bv;
    }
    #pragma unroll
    for (int mt = 0; mt < 2; ++mt)
        #pragma unroll
        for (int r = 0; r < 4; ++r) {
            int m = m0 + Mw + mt*16 + quad*4 + r;
            #pragma unroll
            for (int nt = 0; nt < 2; ++nt)
                C[(size_t)m * N + n0 + Nw + nt*16 + t] = acc[mt][nt][r];
        }
}

// ---------------------------------------------------------------------------
extern "C" void kernel_launch(void* const* d_in, const int* in_sizes, int n_in,
                              void* d_out, int out_size, void* d_ws, size_t ws_size,
                              hipStream_t stream)
{
    const float* x     = (const float*)d_in[0];
    const int*   rpi   = (const int*)d_in[3];
    const float* rct   = (const float*)d_in[4];
    const float* qkvw  = (const float*)d_in[5];
    const float* qkvb  = (const float*)d_in[6];
    const float* qe    = (const float*)d_in[7];
    const float* temp  = (const float*)d_in[8];
    const float* projw = (const float*)d_in[9];
    const float* projb = (const float*)d_in[10];
    const float* fc1w  = (const float*)d_in[11];
    const float* fc1b  = (const float*)d_in[12];
    const float* fc2w  = (const float*)d_in[13];
    const float* fc2b  = (const float*)d_in[14];

    char* p = (char*)d_ws;
    float* tblf  = (float*)p;  p += 131072;
    short* xh    = (short*)p;  p += 4194304;   // reused as y (fp16) after attn
    short* wqh   = (short*)p;  p += 393216;
    short* wph   = (short*)p;  p += 131072;
    short* qh    = (short*)p;  p += 4194304;
    short* kh    = (short*)p;  p += 4194304;
    short* vt    = (short*)p;  p += 4194304;
    short* biasM = (short*)p;  p += 16777216;
    float* out   = (float*)d_out;

    // 1) PREP: fp32->fp16 swizzled conversions + CPB MLP (one launch)
    prep_kernel<<<1215, 256, 0, stream>>>(x, xh, qkvw, wqh, projw, wph,
                                          rct, fc1w, fc1b, fc2w, fc2b, tblf);

    // 2) QKV GEMM (+fused l2norm/scale + V transpose) co-running with
    //    fragment-ordered bf16 bias materialization (one launch)
    qkv_bias_kernel<<<1280, 256, 0, stream>>>(xh, wqh, qkvb, qh, kh, vt,
                                              qe, temp, tblf, rpi, biasM);

    // 3) MFMA attention (fp16 QK^T, exp2 domain, LDS-staged K/V) -> fp16 y
    attn_mfma<<<1024, 256, 0, stream>>>(qh, kh, vt, biasM, xh);

    // 4) output projection (fp16 1-pass, TM=64, 512 blocks) -> d_out (fp32)
    dim3 g2(256/64, 8192/64);
    gemm_proj<<<g2, 256, 0, stream>>>(xh, wph, projb, out, 256);
}

// Round 11
// 147.533 us; speedup vs baseline: 1.1184x; 1.0318x over previous
//
#include <hip/hip_runtime.h>
#include <hip/hip_bf16.h>
#include <cstddef>
#include <cstdint>

typedef float v4f __attribute__((ext_vector_type(4)));
typedef short v8s __attribute__((ext_vector_type(8)));
typedef _Float16 v8h __attribute__((ext_vector_type(8)));

__device__ __forceinline__ uint32_t fbits(float x){ uint32_t u; __builtin_memcpy(&u,&x,4); return u; }
__device__ __forceinline__ float ffrom(uint32_t u){ float f; __builtin_memcpy(&f,&u,4); return f; }
// round-half-up bf16
__device__ __forceinline__ short bf_rh(float x){ return (short)((fbits(x)+0x8000u)>>16); }
__device__ __forceinline__ uint32_t pack_bf_rh(float a, float b){
    uint32_t ua = fbits(a)+0x8000u, ub = fbits(b)+0x8000u;
#if __has_builtin(__builtin_amdgcn_perm)
    return __builtin_amdgcn_perm(ub, ua, 0x07060302u);
#else
    return (ua>>16) | (ub & 0xFFFF0000u);
#endif
}
// fp16 (RNE) stored in a short
__device__ __forceinline__ short f2h(float x){ _Float16 h = (_Float16)x; short s; __builtin_memcpy(&s,&h,2); return s; }
#if __has_builtin(__builtin_amdgcn_exp2f)
#define EXP2(x) __builtin_amdgcn_exp2f(x)
#else
#define EXP2(x) exp2f(x)
#endif

__device__ __forceinline__ void gld16(const void* g, void* l) {
    __builtin_amdgcn_global_load_lds(
        (const __attribute__((address_space(1))) unsigned int*)g,
        (__attribute__((address_space(3))) unsigned int*)l, 16, 0, 0);
}
#define MFMA(a,b,c)  __builtin_amdgcn_mfma_f32_16x16x32_bf16((a),(b),(c),0,0,0)
#define MFMAH(a,b,c) __builtin_amdgcn_mfma_f32_16x16x32_f16((a),(b),(c),0,0,0)

#define LOG2E 1.4426950408889634f

// ---------------------------------------------------------------------------
// PREP (merged): blocks 0..1151 convert x/qkv_w/proj_w fp32 -> fp16 with the
// 16B-chunk swizzle (chunk c of row m at c^(m&7) within its 64-elem K-tile);
// blocks 1152..1214 run the CPB MLP (63 rows each, 4 threads/row, shuffle
// reduce) -> fp32 table [8][3969]. Independent work, one launch.
// ---------------------------------------------------------------------------
__global__ __launch_bounds__(256)
void prep_kernel(const float* __restrict__ x,  short* __restrict__ xh,
                 const float* __restrict__ wq, short* __restrict__ wqh,
                 const float* __restrict__ wp, short* __restrict__ wph,
                 const float* __restrict__ rct,
                 const float* __restrict__ fc1w, const float* __restrict__ fc1b,
                 const float* __restrict__ fc2w, const float* __restrict__ fc2b,
                 float* __restrict__ table)
{
    __shared__ float s1[1024];
    __shared__ float sb[512];
    __shared__ float s2[4096];
    int bid = blockIdx.x;
    int tid = threadIdx.x;
    if (bid < 1152) {
        const float* src; short* dh; int base8;
        if (bid < 1024)      { src = x;  dh = xh;  base8 = bid * 256; }
        else if (bid < 1120) { src = wq; dh = wqh; base8 = (bid-1024) * 256; }
        else                 { src = wp; dh = wph; base8 = (bid-1120) * 256; }
        int e0 = (base8 + tid) * 8;
        int m  = e0 >> 8;
        int k  = e0 & 255;
        int kt = k >> 6, c = (k >> 3) & 7;
        float4 f0 = *(const float4*)(src + e0);
        float4 f1 = *(const float4*)(src + e0 + 4);
        float v[8] = {f0.x,f0.y,f0.z,f0.w,f1.x,f1.y,f1.z,f1.w};
        v8s hi;
        #pragma unroll
        for (int j = 0; j < 8; ++j) hi[j] = f2h(v[j]);
        int dst = m*256 + kt*64 + ((c ^ (m & 7)) << 3);
        *(v8s*)&dh[dst] = hi;
    } else {
        int cbid = bid - 1152;
        for (int i = tid; i < 1024; i += 256) s1[i] = fc1w[i];
        for (int i = tid; i < 512;  i += 256) sb[i] = fc1b[i];
        for (int i = tid; i < 4096; i += 256) s2[i] = fc2w[i];
        __syncthreads();
        int rl = tid >> 2, jp = tid & 3;
        bool ok = rl < 63;
        int r = cbid * 63 + rl;
        float c0 = ok ? rct[2*r]   : 0.f;
        float c1 = ok ? rct[2*r+1] : 0.f;
        float a[8] = {0,0,0,0,0,0,0,0};
        int j0 = jp * 128;
        #pragma unroll 4
        for (int j = j0; j < j0 + 128; ++j) {
            float hv = fmaxf(c0*s1[2*j] + c1*s1[2*j+1] + sb[j], 0.0f);
            #pragma unroll
            for (int hh = 0; hh < 8; ++hh) a[hh] += hv * s2[hh*512 + j];
        }
        #pragma unroll
        for (int hh = 0; hh < 8; ++hh) {
            a[hh] += __shfl_xor(a[hh], 1);
            a[hh] += __shfl_xor(a[hh], 2);
        }
        if (ok && jp == 0) {
            #pragma unroll
            for (int hh = 0; hh < 8; ++hh) table[hh*3969 + r] = a[hh] + fc2b[hh];
        }
    }
}

// ---------------------------------------------------------------------------
// QKV GEMM + BIAS MATERIALIZATION (merged, independent halves):
// blocks 0..767: fp16 1-pass MFMA GEMM qkv = x @ qkv_w^T + b, TM=128 TN=64
//   BK=128 (double-staged), fused epilogue:
//   q: l2norm + qe + softplus(temp)*10 (log2e folded), fp16 plain layout;
//   k: l2norm, fp16 KEY-PERMUTED within 64-tiles + chunk-swizzled;
//   v: bf16 transposed to vt[bh][32][1024] (chunk-swizzled) via LDS.
// blocks 768..1279: bias_mat — bf16 bias scaled by log2(e) in MFMA C-frag
//   order matching permuted keys (key kt*64 + 4t + g), 16 MB.
// ---------------------------------------------------------------------------
__global__ __launch_bounds__(256)
void qkv_bias_kernel(const short* __restrict__ xh, const short* __restrict__ wqh,
                     const float* __restrict__ qkvb,
                     short* __restrict__ qh, short* __restrict__ kh,
                     short* __restrict__ vt,
                     const float* __restrict__ qe, const float* __restrict__ temp,
                     const float* __restrict__ tblf, const int* __restrict__ rpi,
                     short* __restrict__ biasM)
{
    __shared__ __align__(16) char smem[49152];
    int bid  = blockIdx.x;
    int tid  = threadIdx.x;
    int w    = tid >> 6;
    int lane = tid & 63;
    int t    = lane & 15;
    int quad = lane >> 4;

    if (bid < 768) {
        short* A0 = (short*)smem;          // [128][64] fp16, k-tile even
        short* A1 = A0 + 128*64;
        short* W0 = A1 + 128*64;           // [64][64]
        short* W1 = W0 + 64*64;
        int n0 = (bid % 12) * 64, m0 = (bid / 12) * 128;
        int Mw = (w >> 1) * 64, Nw = (w & 1) * 32;

        v4f acc[4][2];
        #pragma unroll
        for (int mt = 0; mt < 4; ++mt)
            #pragma unroll
            for (int nt = 0; nt < 2; ++nt) acc[mt][nt] = (v4f){0,0,0,0};

        int lr8 = lane >> 3, lc8 = lane & 7;
        #pragma unroll 1
        for (int kt2 = 0; kt2 < 2; ++kt2) {
            __syncthreads();
            #pragma unroll
            for (int half = 0; half < 2; ++half) {
                int kt = kt2*2 + half;
                short* Ad = half ? A1 : A0;
                short* Wd = half ? W1 : W0;
                #pragma unroll
                for (int i = 0; i < 4; ++i) {
                    size_t grow = (size_t)(m0 + w*32 + i*8 + lr8) * 256 + kt*64 + lc8*8;
                    gld16(xh + grow, Ad + (w*32 + i*8) * 64);
                }
                #pragma unroll
                for (int i = 0; i < 2; ++i) {
                    size_t grow = (size_t)(n0 + w*16 + i*8 + lr8) * 256 + kt*64 + lc8*8;
                    gld16(wqh + grow, Wd + (w*16 + i*8) * 64);
                }
            }
            __syncthreads();
            #pragma unroll
            for (int half = 0; half < 2; ++half) {
                const short* As = half ? A1 : A0;
                const short* Ws = half ? W1 : W0;
                #pragma unroll
                for (int kk = 0; kk < 2; ++kk) {
                    int cp = ((kk*4 + quad) ^ (t & 7)) << 3;
                    v8h bh8[2];
                    #pragma unroll
                    for (int nt = 0; nt < 2; ++nt)
                        bh8[nt] = *(const v8h*)&Ws[(Nw + nt*16 + t)*64 + cp];
                    #pragma unroll
                    for (int mt = 0; mt < 4; ++mt) {
                        v8h ah = *(const v8h*)&As[(Mw + mt*16 + t)*64 + cp];
                        #pragma unroll
                        for (int nt = 0; nt < 2; ++nt)
                            acc[mt][nt] = MFMAH(ah, bh8[nt], acc[mt][nt]);
                    }
                }
            }
        }

        // bias
        #pragma unroll
        for (int nt = 0; nt < 2; ++nt) {
            float bv = qkvb[n0 + Nw + nt*16 + t];
            #pragma unroll
            for (int mt = 0; mt < 4; ++mt)
                #pragma unroll
                for (int r = 0; r < 4; ++r) acc[mt][nt][r] += bv;
        }

        int which = n0 >> 8;
        if (which < 2) {
            int head = ((n0 + Nw) >> 5) & 7;
            float scale = 0.f;
            if (which == 0)
                scale = log1pf(__expf(temp[head])) * 10.0f;  // softplus*ln(1024)*log2e
            #pragma unroll
            for (int mt = 0; mt < 4; ++mt)
                #pragma unroll
                for (int r = 0; r < 4; ++r) {
                    float a0 = acc[mt][0][r], a1 = acc[mt][1][r];
                    float s = a0*a0 + a1*a1;
                    s += __shfl_xor(s, 1); s += __shfl_xor(s, 2);
                    s += __shfl_xor(s, 4); s += __shfl_xor(s, 8);
                    float inv = 1.0f / fmaxf(sqrtf(s), 1e-12f);
                    int m = m0 + Mw + mt*16 + quad*4 + r;
                    int b = m >> 10, nrow = m & 1023;
                    if (which == 0) {
                        size_t rowoff = (((size_t)b*8 + head)*1024 + nrow) * 32;
                        #pragma unroll
                        for (int nt = 0; nt < 2; ++nt) {
                            int d = nt*16 + t;
                            float val = (acc[mt][nt][r] * inv + qe[head*32 + d]) * scale;
                            qh[rowoff + d] = f2h(val);
                        }
                    } else {
                        int kk = nrow & 63;
                        int p  = (kk & 3)*16 + (kk >> 2);
                        int prow = (nrow & ~63) | p;
                        int swk = (kk >> 3) & 3;
                        size_t rowoff = (((size_t)b*8 + head)*1024 + prow) * 32;
                        #pragma unroll
                        for (int nt = 0; nt < 2; ++nt) {
                            int d = nt*16 + t;
                            int dpos = (((d >> 3) ^ swk) << 3) | (d & 7);
                            kh[rowoff + dpos] = f2h(acc[mt][nt][r] * inv);
                        }
                    }
                }
        } else {
            // v: transpose via LDS, write vt[bh][dim][key] bf16, tile-swizzled
            __syncthreads();
            short* VT = (short*)smem;        // [64][136]
            #pragma unroll
            for (int mt = 0; mt < 4; ++mt)
                #pragma unroll
                for (int nt = 0; nt < 2; ++nt) {
                    int cl = Nw + nt*16 + t;
                    #pragma unroll
                    for (int r = 0; r < 4; ++r) {
                        int rl = Mw + mt*16 + quad*4 + r;
                        VT[cl*136 + rl] = bf_rh(acc[mt][nt][r]);
                    }
                }
            __syncthreads();
            int b = m0 >> 10;
            int keybase = m0 & 1023;
            int headbase = ((n0 - 512) >> 5) & 7;
            int cl = tid >> 2;
            int dim = cl & 31;
            int hd  = headbase + (cl >> 5);
            size_t obase = (((size_t)b*8 + hd)*32 + dim) * 1024 + keybase;
            #pragma unroll
            for (int p = 0; p < 4; ++p) {
                int ci  = (tid & 3) * 4 + p;
                int ktl = ci >> 3, c = ci & 7;
                v8s val = *(const v8s*)&VT[cl*136 + ktl*64 + c*8];
                *(v8s*)&vt[obase + ktl*64 + ((c ^ (dim & 7)) << 3)] = val;
            }
        }
    } else {
        // ------- bias_mat half -------
        float* tb = (float*)smem;            // [3969]
        int b2  = bid - 768;
        int h   = b2 >> 6;
        int q16 = b2 & 63;
        for (int i = tid; i < 3969; i += 256) tb[i] = tblf[h*3969 + i] * LOG2E;
        __syncthreads();
        int row0 = q16*16 + quad*4;
        #pragma unroll 1
        for (int kk = 0; kk < 4; ++kk) {
            int kt = w*4 + kk;
            #pragma unroll
            for (int g = 0; g < 4; ++g) {
                float o[4];
                #pragma unroll
                for (int r = 0; r < 4; ++r)
                    o[r] = tb[rpi[(size_t)(row0 + r)*1024 + kt*64 + 4*t + g]];
                uint2 pk;
                pk.x = pack_bf_rh(o[0], o[1]);
                pk.y = pack_bf_rh(o[2], o[3]);
                size_t base = ((((size_t)(h*64 + q16)*16 + kt)*4 + g)*64 + lane)*4;
                *(uint2*)(biasM + base) = pk;
            }
        }
    }
}

// ---------------------------------------------------------------------------
// MFMA flash attention, exp2 domain, fp16 QK^T, bf16 PV. Q-tile = 128 rows,
// 8 waves (512 threads), 512 blocks: K/V staged ONCE per 128 Q-rows (waves
// 0-3 stage K quarters, 4-7 stage V quarters — 1 gld16/wave/tile), halving
// staging DMA and K/V L2 traffic vs the 64-row version. Double-buffered LDS,
// bf16 bias as MFMA C-init (register-pipelined), key-permuted K so P stores
// are packed b64 writes. Output: swizzled fp16 y for the 1-pass proj GEMM.
// ---------------------------------------------------------------------------
__global__ __launch_bounds__(512)
void attn_mfma(const short* __restrict__ qh, const short* __restrict__ kh,
               const short* __restrict__ vt,  const short* __restrict__ biasM,
               short* __restrict__ yh)
{
    __shared__ __align__(16) short Kh_s[2][2048];   // [64][32] fp16
    __shared__ __align__(16) short Vt_s[2][2048];   // [32][64] bf16
    __shared__ __align__(16) short Ps[8][16][68];   // per-wave P (bf16, cols=keys)

    int bh  = blockIdx.x >> 3;
    int qt  = blockIdx.x & 7;
    int h   = bh & 7;
    int b   = bh >> 3;
    int tid = threadIdx.x;
    int w    = tid >> 6;        // 0..7
    int lane = tid & 63;
    int t    = lane & 15;
    int quad = lane >> 4;

    size_t qoff = ((size_t)bh*1024 + qt*128 + w*16 + t) * 32 + quad*8;
    v8h qf = *(const v8h*)(qh + qoff);

    v4f Oacc[2] = {{0,0,0,0},{0,0,0,0}};
    float lsum[4] = {0,0,0,0};

    size_t kgbase = (size_t)bh * 32768;
    const short* bmb = biasM + ((size_t)(h*64 + qt*8 + w) * 16) * 1024 + lane*4;
    int qrow0 = qt*128 + w*16 + quad*4;
    int swzS = (quad ^ ((t >> 1) & 3)) << 3;
    int lr8 = lane >> 3, lc8 = lane & 7;

    // stage tile 0 into buffer 0 (1 gld16 per wave: w<4 -> K, w>=4 -> V)
    if (w < 4)
        gld16(kh + kgbase + w*512 + lane*8, &Kh_s[0][w*512]);
    else
        gld16(vt + kgbase + (size_t)((w-4)*8 + lr8)*1024 + lc8*8, &Vt_s[0][(w-4)*512]);
    uint2 curb[4];
    #pragma unroll
    for (int g = 0; g < 4; ++g) curb[g] = *(const uint2*)(bmb + g*256);

    #pragma unroll 1
    for (int kt = 0; kt < 16; ++kt) {
        int cur = kt & 1;
        __syncthreads();   // prior tile's loads landed; prior reads of nb done
        uint2 nxtb[4];
        if (kt < 15) {
            int nkt = kt + 1, nb = cur ^ 1;
            if (w < 4)
                gld16(kh + kgbase + (size_t)nkt*2048 + w*512 + lane*8, &Kh_s[nb][w*512]);
            else
                gld16(vt + kgbase + (size_t)((w-4)*8 + lr8)*1024 + nkt*64 + lc8*8,
                      &Vt_s[nb][(w-4)*512]);
            const short* bp = bmb + (size_t)nkt*1024;
            #pragma unroll
            for (int g = 0; g < 4; ++g) nxtb[g] = *(const uint2*)(bp + g*256);
        }

        // S = bias + Q K^T (fp16, 1 pass), exp2 domain
        v4f S[4];
        #pragma unroll
        for (int g = 0; g < 4; ++g) {
            v8h kb = *(const v8h*)&Kh_s[cur][(g*16 + t)*32 + swzS];
            v4f c;
            c[0] = ffrom(curb[g].x << 16);
            c[1] = ffrom(curb[g].x & 0xFFFF0000u);
            c[2] = ffrom(curb[g].y << 16);
            c[3] = ffrom(curb[g].y & 0xFFFF0000u);
            S[g] = MFMAH(qf, kb, c);
        }

        // p = exp2(S); P cols are contiguous actual keys 4t+g -> packed b64
        #pragma unroll
        for (int r = 0; r < 4; ++r) {
            float p0 = EXP2(S[0][r]);
            float p1 = EXP2(S[1][r]);
            float p2 = EXP2(S[2][r]);
            float p3 = EXP2(S[3][r]);
            lsum[r] += (p0 + p1) + (p2 + p3);
            uint2 pk;
            pk.x = pack_bf_rh(p0, p1);
            pk.y = pack_bf_rh(p2, p3);
            *(uint2*)&Ps[w][quad*4 + r][t*4] = pk;
        }

        // O += P V (same-wave LDS dependency, no barrier)
        #pragma unroll
        for (int ks = 0; ks < 2; ++ks) {
            v8s pf = *(const v8s*)&Ps[w][t][ks*32 + quad*8];
            int vsw = ((ks*4 + quad) ^ (t & 7)) << 3;
            #pragma unroll
            for (int g = 0; g < 2; ++g) {
                v8s vf = *(const v8s*)&Vt_s[cur][(g*16 + t)*64 + vsw];
                Oacc[g] = MFMA(pf, vf, Oacc[g]);
            }
        }
        #pragma unroll
        for (int g = 0; g < 4; ++g) curb[g] = nxtb[g];
    }

    // epilogue: reduce l, normalize, write swizzled fp16 y
    #pragma unroll
    for (int r = 0; r < 4; ++r) {
        float l = lsum[r];
        l += __shfl_xor(l, 1); l += __shfl_xor(l, 2);
        l += __shfl_xor(l, 4); l += __shfl_xor(l, 8);
        float inv = 1.0f / l;
        int qrow = qrow0 + r;
        int m = b*1024 + qrow;
        size_t mbase = (size_t)m * 256;
        int mk = m & 7;
        #pragma unroll
        for (int g = 0; g < 2; ++g) {
            float o = Oacc[g][r] * inv;
            int c = h*4 + g*2 + (t >> 3);
            int chp = ((c ^ mk) << 3) | (t & 7);
            yh[mbase + chp] = f2h(o);
        }
    }
}

// ---------------------------------------------------------------------------
// Output projection: fp16 1-pass MFMA GEMM, TM=64 TN=64 (512 blocks ->
// 2 blocks/CU, 2 waves/SIMD vs 1 for TM=128), BK=128 double-staged.
// ---------------------------------------------------------------------------
__global__ __launch_bounds__(256)
void gemm_proj(const short* __restrict__ Ah_g, const short* __restrict__ Wh_g,
               const float* __restrict__ bias, float* __restrict__ C, int N)
{
    __shared__ __align__(16) short As[2][4096];   // [64][64] fp16 per buf
    __shared__ __align__(16) short Ws[2][4096];

    int tid  = threadIdx.x;
    int w    = tid >> 6;
    int lane = tid & 63;
    int t    = lane & 15;
    int quad = lane >> 4;
    int m0 = blockIdx.y * 64, n0 = blockIdx.x * 64;
    int Mw = (w >> 1) * 32, Nw = (w & 1) * 32;

    v4f acc[2][2];
    #pragma unroll
    for (int mt = 0; mt < 2; ++mt)
        #pragma unroll
        for (int nt = 0; nt < 2; ++nt) acc[mt][nt] = (v4f){0,0,0,0};

    int lr8 = lane >> 3, lc8 = lane & 7;
    #pragma unroll 1
    for (int kt2 = 0; kt2 < 2; ++kt2) {
        __syncthreads();
        #pragma unroll
        for (int half = 0; half < 2; ++half) {
            int kt = kt2*2 + half;
            #pragma unroll
            for (int i = 0; i < 2; ++i) {
                size_t grow = (size_t)(m0 + w*16 + i*8 + lr8) * 256 + kt*64 + lc8*8;
                gld16(Ah_g + grow, &As[half][(w*16 + i*8) * 64]);
            }
            #pragma unroll
            for (int i = 0; i < 2; ++i) {
                size_t grow = (size_t)(n0 + w*16 + i*8 + lr8) * 256 + kt*64 + lc8*8;
                gld16(Wh_g + grow, &Ws[half][(w*16 + i*8) * 64]);
            }
        }
        __syncthreads();
        #pragma unroll
        for (int half = 0; half < 2; ++half) {
            #pragma unroll
            for (int kk = 0; kk < 2; ++kk) {
                int cp = ((kk*4 + quad) ^ (t & 7)) << 3;
                v8h bh8[2];
                #pragma unroll
                for (int nt = 0; nt < 2; ++nt)
                    bh8[nt] = *(const v8h*)&Ws[half][(Nw + nt*16 + t)*64 + cp];
                #pragma unroll
                for (int mt = 0; mt < 2; ++mt) {
                    v8h ah = *(const v8h*)&As[half][(Mw + mt*16 + t)*64 + cp];
                    #pragma unroll
                    for (int nt = 0; nt < 2; ++nt)
                        acc[mt][nt] = MFMAH(ah, bh8[nt], acc[mt][nt]);
                }
            }
        }
    }

    #pragma unroll
    for (int nt = 0; nt < 2; ++nt) {
        float bv = bias[n0 + Nw + nt*16 + t];
        #pragma unroll
        for (int mt = 0; mt < 2; ++mt)
            #pragma unroll
            for (int r = 0; r < 4; ++r) acc[mt][nt][r] += bv;
    }
    #pragma unroll
    for (int mt = 0; mt < 2; ++mt)
        #pragma unroll
        for (int r = 0; r < 4; ++r) {
            int m = m0 + Mw + mt*16 + quad*4 + r;
            #pragma unroll
            for (int nt = 0; nt < 2; ++nt)
                C[(size_t)m * N + n0 + Nw + nt*16 + t] = acc[mt][nt][r];
        }
}

// ---------------------------------------------------------------------------
extern "C" void kernel_launch(void* const* d_in, const int* in_sizes, int n_in,
                              void* d_out, int out_size, void* d_ws, size_t ws_size,
                              hipStream_t stream)
{
    const float* x     = (const float*)d_in[0];
    const int*   rpi   = (const int*)d_in[3];
    const float* rct   = (const float*)d_in[4];
    const float* qkvw  = (const float*)d_in[5];
    const float* qkvb  = (const float*)d_in[6];
    const float* qe    = (const float*)d_in[7];
    const float* temp  = (const float*)d_in[8];
    const float* projw = (const float*)d_in[9];
    const float* projb = (const float*)d_in[10];
    const float* fc1w  = (const float*)d_in[11];
    const float* fc1b  = (const float*)d_in[12];
    const float* fc2w  = (const float*)d_in[13];
    const float* fc2b  = (const float*)d_in[14];

    char* p = (char*)d_ws;
    float* tblf  = (float*)p;  p += 131072;
    short* xh    = (short*)p;  p += 4194304;   // reused as y (fp16) after attn
    short* wqh   = (short*)p;  p += 393216;
    short* wph   = (short*)p;  p += 131072;
    short* qh    = (short*)p;  p += 4194304;
    short* kh    = (short*)p;  p += 4194304;
    short* vt    = (short*)p;  p += 4194304;
    short* biasM = (short*)p;  p += 16777216;
    float* out   = (float*)d_out;

    // 1) PREP: fp32->fp16 swizzled conversions + CPB MLP (one launch)
    prep_kernel<<<1215, 256, 0, stream>>>(x, xh, qkvw, wqh, projw, wph,
                                          rct, fc1w, fc1b, fc2w, fc2b, tblf);

    // 2) QKV GEMM (+fused l2norm/scale + V transpose) co-running with
    //    fragment-ordered bf16 bias materialization (one launch)
    qkv_bias_kernel<<<1280, 256, 0, stream>>>(xh, wqh, qkvb, qh, kh, vt,
                                              qe, temp, tblf, rpi, biasM);

    // 3) MFMA attention (fp16 QK^T, exp2 domain, Q-tile=128, 8 waves) -> fp16 y
    attn_mfma<<<512, 512, 0, stream>>>(qh, kh, vt, biasM, xh);

    // 4) output projection (fp16 1-pass, TM=64, 512 blocks) -> d_out (fp32)
    dim3 g2(256/64, 8192/64);
    gemm_proj<<<g2, 256, 0, stream>>>(xh, wph, projb, out, 256);
}